// Round 1
// baseline (343.457 us; speedup 1.0000x reference)
//
#include <hip/hip_runtime.h>
#include <hip/hip_bf16.h>
#include <cstdint>

#define BB 64
#define TT 200
#define KN 2000
#define VV 128

typedef __attribute__((ext_vector_type(8))) short bf16x8;
typedef __attribute__((ext_vector_type(4))) float f32x4;

// ws layout (floats): pd[384] @0, pr[384] @384, uc[128] @768, ud[128] @896,
// ur[128] @1024, gam[12800] @1152, newc[12800] @13952  (total 26752 floats)

__device__ __forceinline__ float sigm(float x) { return 1.f / (1.f + __expf(-x)); }
__device__ __forceinline__ float tanh_f(float x) {
    float e = __expf(2.f * x);
    return (e - 1.f) / (e + 1.f);
}

// ---------------- precompute: gamma gather + small projection vectors ----------
__global__ void pre_kernel(const int* __restrict__ d_seq, const float* __restrict__ D_emb,
                           const float* __restrict__ v_d, const float* __restrict__ v_r,
                           const float* __restrict__ v_c, const float* __restrict__ W_ih,
                           const float* __restrict__ W2a, float* __restrict__ ws)
{
    int g = blockIdx.x * 256 + threadIdx.x;
    float* pd = ws;
    float* pr = ws + 384;
    float* uc = ws + 768;
    float* ud = ws + 896;
    float* ur = ws + 1024;
    float* gam = ws + 1152;
    if (g < BB * TT) gam[g] = D_emb[d_seq[g]];
    if (g < 384) {
        float a = 0.f, b = 0.f;
        for (int k = 0; k < VV; ++k) {
            a = fmaf(W_ih[g * 256 + k], v_d[k], a);
            b = fmaf(W_ih[g * 256 + VV + k], v_r[k], b);
        }
        pd[g] = a; pr[g] = b;
    }
    if (g < VV) {
        float a = 0.f, b = 0.f, c = 0.f;
        for (int k = 0; k < VV; ++k) {
            a = fmaf(W2a[g * 384 + k], v_c[k], a);
            b = fmaf(W2a[g * 384 + VV + k], v_d[k], b);
            c = fmaf(W2a[g * 384 + 2 * VV + k], v_r[k], c);
        }
        uc[g] = a; ud[g] = b; ur[g] = c;
    }
}

// ---------------- memory scan: one wave per batch row, C-state in LDS ----------
__global__ void mem_kernel(const int* __restrict__ c_seq, const float* __restrict__ r_seq,
                           const float* __restrict__ W2b, const float* __restrict__ b2a,
                           const float* __restrict__ b2b, const float* __restrict__ ws,
                           float* __restrict__ newc_out)
{
    const float* uc = ws + 768;
    const float* ud = ws + 896;
    const float* ur = ws + 1024;
    const float* gam = ws + 1152;
    int b = blockIdx.x, l = threadIdx.x;  // 64 threads = 1 wave
    __shared__ float C[KN];
    __shared__ float gam_row[TT], r_row[TT];
    __shared__ int c_row[TT];
    for (int i = l; i < KN; i += 64) C[i] = 0.f;
    for (int i = l; i < TT; i += 64) {
        gam_row[i] = gam[b * TT + i];
        r_row[i] = r_seq[b * TT + i];
        c_row[i] = c_seq[b * TT + i];
    }
    float uc0 = uc[l], uc1 = uc[l + 64];
    float ud0 = ud[l], ud1 = ud[l + 64];
    float ur0 = ur[l], ur1 = ur[l + 64];
    float ba0 = b2a[l], ba1 = b2a[l + 64];
    float wb0 = W2b[l], wb1 = W2b[l + 64];
    float bb = b2b[0];
    __syncthreads();
    for (int t = 0; t < TT; ++t) {
        int ct = c_row[t];
        float beta = C[ct];
        float g = gam_row[t], rr = r_row[t];
        float h0 = fmaxf(fmaf(beta, uc0, fmaf(g, ud0, fmaf(rr, ur0, ba0))), 0.f);
        float h1 = fmaxf(fmaf(beta, uc1, fmaf(g, ud1, fmaf(rr, ur1, ba1))), 0.f);
        float p = fmaf(h0, wb0, h1 * wb1);
        #pragma unroll
        for (int m = 32; m > 0; m >>= 1) p += __shfl_xor(p, m);
        float nc = p + bb;
        if (l == 0) {
            C[ct] = nc;
            newc_out[b * TT + t] = nc;
        }
    }
}

// ---------------- C_seq fill: parallel reconstruction, coalesced in k ----------
__global__ void fill_kernel(const int* __restrict__ c_seq, const float* __restrict__ newc,
                            float* __restrict__ C_out)
{
    int b = blockIdx.x >> 3;
    int kc = blockIdx.x & 7;
    int k = kc * 256 + threadIdx.x;
    __shared__ int c_row[TT];
    __shared__ float n_row[TT];
    for (int i = threadIdx.x; i < TT; i += 256) {
        c_row[i] = c_seq[b * TT + i];
        n_row[i] = newc[b * TT + i];
    }
    __syncthreads();
    if (k >= KN) return;
    float cur = 0.f;
    float* outp = C_out + (size_t)b * TT * KN + k;
    for (int t = 0; t < TT; ++t) {
        if (c_row[t] == k) cur = n_row[t];
        outp[(size_t)t * KN] = cur;
    }
}

// ---------------- GRU scan: 1 block per batch row, W_hh rows in registers ------
__global__ __launch_bounds__(384, 2) void gru_kernel(
    const float* __restrict__ r_seq, const float* __restrict__ Whh,
    const float* __restrict__ bih, const float* __restrict__ bhh,
    const float* __restrict__ ws, float* __restrict__ h_out)
{
    const float* pd = ws;
    const float* pr = ws + 384;
    const float* gam = ws + 1152;
    int b = blockIdx.x, j = threadIdx.x;
    __shared__ __align__(16) float h_lds[VV];
    __shared__ float gh_lds[384];
    __shared__ float gam_row[TT], r_row[TT];
    for (int t = j; t < TT; t += 384) {
        gam_row[t] = gam[b * TT + t];
        r_row[t] = r_seq[b * TT + t];
    }
    if (j < VV) h_lds[j] = 0.f;
    float w[128];
    #pragma unroll
    for (int q = 0; q < 32; ++q) {
        float4 v = *(const float4*)(Whh + (size_t)j * VV + 4 * q);
        w[4 * q + 0] = v.x; w[4 * q + 1] = v.y;
        w[4 * q + 2] = v.z; w[4 * q + 3] = v.w;
    }
    float bhhj = bhh[j];
    float pdr = 0.f, pdz = 0.f, pdn = 0.f, prr_ = 0.f, prz = 0.f, prn = 0.f;
    float bir = 0.f, biz = 0.f, bin_ = 0.f;
    if (j < VV) {
        pdr = pd[j]; pdz = pd[j + VV]; pdn = pd[j + 2 * VV];
        prr_ = pr[j]; prz = pr[j + VV]; prn = pr[j + 2 * VV];
        bir = bih[j]; biz = bih[j + VV]; bin_ = bih[j + 2 * VV];
    }
    __syncthreads();
    float* hp = h_out + (size_t)b * TT * VV;
    for (int t = 0; t < TT; ++t) {
        float acc0 = 0.f, acc1 = 0.f, acc2 = 0.f, acc3 = 0.f;
        const float4* h4 = (const float4*)h_lds;
        #pragma unroll
        for (int q = 0; q < 32; q += 4) {
            float4 x0 = h4[q], x1 = h4[q + 1], x2 = h4[q + 2], x3 = h4[q + 3];
            acc0 = fmaf(x0.x, w[4 * q + 0], acc0);  acc0 = fmaf(x0.y, w[4 * q + 1], acc0);
            acc0 = fmaf(x0.z, w[4 * q + 2], acc0);  acc0 = fmaf(x0.w, w[4 * q + 3], acc0);
            acc1 = fmaf(x1.x, w[4 * q + 4], acc1);  acc1 = fmaf(x1.y, w[4 * q + 5], acc1);
            acc1 = fmaf(x1.z, w[4 * q + 6], acc1);  acc1 = fmaf(x1.w, w[4 * q + 7], acc1);
            acc2 = fmaf(x2.x, w[4 * q + 8], acc2);  acc2 = fmaf(x2.y, w[4 * q + 9], acc2);
            acc2 = fmaf(x2.z, w[4 * q + 10], acc2); acc2 = fmaf(x2.w, w[4 * q + 11], acc2);
            acc3 = fmaf(x3.x, w[4 * q + 12], acc3); acc3 = fmaf(x3.y, w[4 * q + 13], acc3);
            acc3 = fmaf(x3.z, w[4 * q + 14], acc3); acc3 = fmaf(x3.w, w[4 * q + 15], acc3);
        }
        gh_lds[j] = bhhj + ((acc0 + acc1) + (acc2 + acc3));
        __syncthreads();
        if (j < VV) {
            float g = gam_row[t], rr = r_row[t];
            float ghr = gh_lds[j], ghz = gh_lds[VV + j], ghn = gh_lds[2 * VV + j];
            float r = sigm(fmaf(g, pdr, fmaf(rr, prr_, bir)) + ghr);
            float z = sigm(fmaf(g, pdz, fmaf(rr, prz, biz)) + ghz);
            float n = tanh_f(fmaf(g, pdn, fmaf(rr, prn, bin_)) + r * ghn);
            float h = h_lds[j];
            float hn = fmaf(1.f - z, n, z * h);
            h_lds[j] = hn;
            hp[t * VV + j] = hn;
        }
        __syncthreads();
    }
}

// ---------------- alpha head: bf16 MFMA, fragments loaded straight from global -
__device__ __forceinline__ short f2bf(float f) {
    uint32_t u = __float_as_uint(f);
    u = (u + 0x7FFFu + ((u >> 16) & 1u)) >> 16;
    return (short)u;
}
__device__ __forceinline__ bf16x8 load_cvt8(const float* p) {
    float4 a = *(const float4*)p;
    float4 c = *(const float4*)(p + 4);
    bf16x8 r;
    r[0] = f2bf(a.x); r[1] = f2bf(a.y); r[2] = f2bf(a.z); r[3] = f2bf(a.w);
    r[4] = f2bf(c.x); r[5] = f2bf(c.y); r[6] = f2bf(c.z); r[7] = f2bf(c.w);
    return r;
}

__global__ void alpha_kernel(const float* __restrict__ h_seq, const float* __restrict__ W1a,
                             const float* __restrict__ b1a, const float* __restrict__ W1b,
                             const float* __restrict__ b1b, float* __restrict__ alpha)
{
    int wave = threadIdx.x >> 6;
    int lane = threadIdx.x & 63;
    int tile = blockIdx.x * 4 + wave;  // 800 tiles of 16 rows
    int rowbase = tile * 16;
    int rl = lane & 15, g = lane >> 4;
    const float* hp = h_seq + (size_t)(rowbase + rl) * VV + g * 8;
    bf16x8 a0 = load_cvt8(hp);
    bf16x8 a1 = load_cvt8(hp + 32);
    bf16x8 a2 = load_cvt8(hp + 64);
    bf16x8 a3 = load_cvt8(hp + 96);
    float p0 = 0.f, p1 = 0.f, p2 = 0.f, p3 = 0.f;
    float bb = b1b[0];
    #pragma unroll
    for (int jt = 0; jt < 8; ++jt) {
        int j = jt * 16 + rl;
        const float* wp = W1a + (size_t)j * VV + g * 8;
        f32x4 acc = {0.f, 0.f, 0.f, 0.f};
        acc = __builtin_amdgcn_mfma_f32_16x16x32_bf16(a0, load_cvt8(wp), acc, 0, 0, 0);
        acc = __builtin_amdgcn_mfma_f32_16x16x32_bf16(a1, load_cvt8(wp + 32), acc, 0, 0, 0);
        acc = __builtin_amdgcn_mfma_f32_16x16x32_bf16(a2, load_cvt8(wp + 64), acc, 0, 0, 0);
        acc = __builtin_amdgcn_mfma_f32_16x16x32_bf16(a3, load_cvt8(wp + 96), acc, 0, 0, 0);
        float bj = b1a[j], wj = W1b[j];
        p0 += fmaxf(acc[0] + bj, 0.f) * wj;
        p1 += fmaxf(acc[1] + bj, 0.f) * wj;
        p2 += fmaxf(acc[2] + bj, 0.f) * wj;
        p3 += fmaxf(acc[3] + bj, 0.f) * wj;
    }
    #pragma unroll
    for (int m = 1; m < 16; m <<= 1) {
        p0 += __shfl_xor(p0, m);
        p1 += __shfl_xor(p1, m);
        p2 += __shfl_xor(p2, m);
        p3 += __shfl_xor(p3, m);
    }
    if (rl == 0) {
        alpha[rowbase + g * 4 + 0] = p0 + bb;
        alpha[rowbase + g * 4 + 1] = p1 + bb;
        alpha[rowbase + g * 4 + 2] = p2 + bb;
        alpha[rowbase + g * 4 + 3] = p3 + bb;
    }
}

extern "C" void kernel_launch(void* const* d_in, const int* in_sizes, int n_in,
                              void* d_out, int out_size, void* d_ws, size_t ws_size,
                              hipStream_t stream)
{
    const int*   c_seq = (const int*)d_in[0];
    const int*   d_seq = (const int*)d_in[1];
    const float* r_seq = (const float*)d_in[2];
    const float* D_emb = (const float*)d_in[3];
    const float* v_d   = (const float*)d_in[4];
    const float* v_r   = (const float*)d_in[5];
    const float* v_c   = (const float*)d_in[6];
    const float* W_ih  = (const float*)d_in[7];
    const float* W_hh  = (const float*)d_in[8];
    const float* b_ih  = (const float*)d_in[9];
    const float* b_hh  = (const float*)d_in[10];
    const float* W1a   = (const float*)d_in[11];
    const float* b1a   = (const float*)d_in[12];
    const float* W1b   = (const float*)d_in[13];
    const float* b1b   = (const float*)d_in[14];
    const float* W2a   = (const float*)d_in[15];
    const float* b2a   = (const float*)d_in[16];
    const float* W2b   = (const float*)d_in[17];
    const float* b2b   = (const float*)d_in[18];

    float* out   = (float*)d_out;
    float* alpha = out;                       // 12800
    float* h_seq = out + 12800;               // 1,638,400
    float* C_out = out + 12800 + 1638400;     // 25,600,000
    float* ws    = (float*)d_ws;
    float* newc  = ws + 13952;

    hipLaunchKernelGGL(pre_kernel, dim3(64), dim3(256), 0, stream,
                       d_seq, D_emb, v_d, v_r, v_c, W_ih, W2a, ws);
    hipLaunchKernelGGL(mem_kernel, dim3(BB), dim3(64), 0, stream,
                       c_seq, r_seq, W2b, b2a, b2b, ws, newc);
    hipLaunchKernelGGL(fill_kernel, dim3(BB * 8), dim3(256), 0, stream,
                       c_seq, newc, C_out);
    hipLaunchKernelGGL(gru_kernel, dim3(BB), dim3(384), 0, stream,
                       r_seq, W_hh, b_ih, b_hh, ws, h_seq);
    hipLaunchKernelGGL(alpha_kernel, dim3(200), dim3(256), 0, stream,
                       h_seq, W1a, b1a, W1b, b1b, alpha);
}

// Round 4
// 286.008 us; speedup vs baseline: 1.2009x; 1.2009x over previous
//
#include <hip/hip_runtime.h>
#include <hip/hip_bf16.h>
#include <cstdint>

#define BB 64
#define TT 200
#define KN 2000
#define VV 128

typedef __attribute__((ext_vector_type(8))) short bf16x8;
typedef __attribute__((ext_vector_type(4))) float f32x4;

// ws layout (floats): pd[384] @0, pr[384] @384, uc[128] @768, ud[128] @896,
// ur[128] @1024, gam[12800] @1152, newc[12800] @13952  (total 26752 floats)

__device__ __forceinline__ float sigm(float x) { return 1.f / (1.f + __expf(-x)); }
__device__ __forceinline__ float tanh_f(float x) {
    float e = __expf(2.f * x);
    return (e - 1.f) / (e + 1.f);
}
__device__ __forceinline__ float bcast(float v, int lane) {
    return __int_as_float(__builtin_amdgcn_readlane(__float_as_int(v), lane));
}

// ---------------- precompute: gamma gather + small projection vectors ----------
__global__ void pre_kernel(const int* __restrict__ d_seq, const float* __restrict__ D_emb,
                           const float* __restrict__ v_d, const float* __restrict__ v_r,
                           const float* __restrict__ v_c, const float* __restrict__ W_ih,
                           const float* __restrict__ W2a, float* __restrict__ ws)
{
    int g = blockIdx.x * 256 + threadIdx.x;
    float* pd = ws;
    float* pr = ws + 384;
    float* uc = ws + 768;
    float* ud = ws + 896;
    float* ur = ws + 1024;
    float* gam = ws + 1152;
    if (g < BB * TT) gam[g] = D_emb[d_seq[g]];
    if (g < 384) {
        float a = 0.f, b = 0.f;
        for (int k = 0; k < VV; ++k) {
            a = fmaf(W_ih[g * 256 + k], v_d[k], a);
            b = fmaf(W_ih[g * 256 + VV + k], v_r[k], b);
        }
        pd[g] = a; pr[g] = b;
    }
    if (g < VV) {
        float a = 0.f, b = 0.f, c = 0.f;
        for (int k = 0; k < VV; ++k) {
            a = fmaf(W2a[g * 384 + k], v_c[k], a);
            b = fmaf(W2a[g * 384 + VV + k], v_d[k], b);
            c = fmaf(W2a[g * 384 + 2 * VV + k], v_r[k], c);
        }
        uc[g] = a; ud[g] = b; ur[g] = c;
    }
}

// ---------------- memory scan: one wave per batch row, C-state in LDS ----------
__global__ void mem_kernel(const int* __restrict__ c_seq, const float* __restrict__ r_seq,
                           const float* __restrict__ W2b, const float* __restrict__ b2a,
                           const float* __restrict__ b2b, const float* __restrict__ ws,
                           float* __restrict__ newc_out)
{
    const float* uc = ws + 768;
    const float* ud = ws + 896;
    const float* ur = ws + 1024;
    const float* gam = ws + 1152;
    int b = blockIdx.x, l = threadIdx.x;  // 64 threads = 1 wave
    __shared__ float C[KN];
    __shared__ float gam_row[TT], r_row[TT];
    __shared__ int c_row[TT];
    for (int i = l; i < KN; i += 64) C[i] = 0.f;
    for (int i = l; i < TT; i += 64) {
        gam_row[i] = gam[b * TT + i];
        r_row[i] = r_seq[b * TT + i];
        c_row[i] = c_seq[b * TT + i];
    }
    float uc0 = uc[l], uc1 = uc[l + 64];
    float ud0 = ud[l], ud1 = ud[l + 64];
    float ur0 = ur[l], ur1 = ur[l + 64];
    float ba0 = b2a[l], ba1 = b2a[l + 64];
    float wb0 = W2b[l], wb1 = W2b[l + 64];
    float bb = b2b[0];
    __syncthreads();
    for (int t = 0; t < TT; ++t) {
        int ct = c_row[t];
        float beta = C[ct];
        float g = gam_row[t], rr = r_row[t];
        float h0 = fmaxf(fmaf(beta, uc0, fmaf(g, ud0, fmaf(rr, ur0, ba0))), 0.f);
        float h1 = fmaxf(fmaf(beta, uc1, fmaf(g, ud1, fmaf(rr, ur1, ba1))), 0.f);
        float p = fmaf(h0, wb0, h1 * wb1);
        #pragma unroll
        for (int m = 32; m > 0; m >>= 1) p += __shfl_xor(p, m);
        float nc = p + bb;
        if (l == 0) {
            C[ct] = nc;
            newc_out[b * TT + t] = nc;
        }
    }
}

// ---------------- C_seq fill: parallel reconstruction, coalesced in k ----------
__global__ void fill_kernel(const int* __restrict__ c_seq, const float* __restrict__ newc,
                            float* __restrict__ C_out)
{
    int b = blockIdx.x >> 3;
    int kc = blockIdx.x & 7;
    int k = kc * 256 + threadIdx.x;
    __shared__ int c_row[TT];
    __shared__ float n_row[TT];
    for (int i = threadIdx.x; i < TT; i += 256) {
        c_row[i] = c_seq[b * TT + i];
        n_row[i] = newc[b * TT + i];
    }
    __syncthreads();
    if (k >= KN) return;
    float cur = 0.f;
    float* outp = C_out + (size_t)b * TT * KN + k;
    for (int t = 0; t < TT; ++t) {
        if (c_row[t] == k) cur = n_row[t];
        outp[(size_t)t * KN] = cur;
    }
}

// ---------------- GRU scan: readlane/SGPR-broadcast matvec, 8 waves -----------
// 512 threads. wave w: jg = w>>2 (j-base jg*192), kg = w&3 (k range [kg*32,kg*32+32)).
// Lane l owns outputs j0=jg*192+l, j0+64, j0+128 over its 32-wide k chunk.
// h broadcast: one ds_read_b128 puts h[k0+4q..k0+4q+3] in lane q (q<8); v_readlane
// feeds v_fmac_f32 with an SGPR operand (no per-thread LDS re-reads of h).
// Global h store batched via 8-step LDS history (one vmcnt drain per 8 steps).
__global__ __launch_bounds__(512, 1) void gru_kernel(
    const float* __restrict__ r_seq, const float* __restrict__ Whh,
    const float* __restrict__ bih, const float* __restrict__ bhh,
    const float* __restrict__ ws, float* __restrict__ h_out)
{
    const float* pd = ws;
    const float* pr = ws + 384;
    const float* gam = ws + 1152;
    int b = blockIdx.x, tid = threadIdx.x;
    int wid = tid >> 6, l = tid & 63;
    int jg = wid >> 2, kg = wid & 3;
    int j0 = jg * 192 + l;
    int k0 = kg * 32;

    __shared__ __align__(16) float h_lds[VV];
    __shared__ float P[4][384];
    __shared__ __align__(16) float hist[8][VV];
    __shared__ float gam_row[TT], r_row[TT];

    for (int t = tid; t < TT; t += 512) {
        gam_row[t] = gam[b * TT + t];
        r_row[t] = r_seq[b * TT + t];
    }
    if (tid < VV) h_lds[tid] = 0.f;

    // per-thread weight slices: w0/w1/w2[q] = Whh[j0 + {0,64,128}][k0+q]
    float w0[32], w1[32], w2[32];
    #pragma unroll
    for (int q = 0; q < 8; ++q) {
        float4 a = *(const float4*)(Whh + (size_t)j0 * VV + k0 + 4 * q);
        float4 c = *(const float4*)(Whh + (size_t)(j0 + 64) * VV + k0 + 4 * q);
        float4 d = *(const float4*)(Whh + (size_t)(j0 + 128) * VV + k0 + 4 * q);
        w0[4 * q] = a.x; w0[4 * q + 1] = a.y; w0[4 * q + 2] = a.z; w0[4 * q + 3] = a.w;
        w1[4 * q] = c.x; w1[4 * q + 1] = c.y; w1[4 * q + 2] = c.z; w1[4 * q + 3] = c.w;
        w2[4 * q] = d.x; w2[4 * q + 1] = d.y; w2[4 * q + 2] = d.z; w2[4 * q + 3] = d.w;
    }

    // gate-thread preloads (n = tid < 128)
    float bhr = 0.f, bhz = 0.f, bhn = 0.f;
    float pdr = 0.f, pdz = 0.f, pdn = 0.f, prr_ = 0.f, prz = 0.f, prn = 0.f;
    float bir = 0.f, biz = 0.f, bin_ = 0.f;
    if (tid < VV) {
        int n = tid;
        bhr = bhh[n]; bhz = bhh[n + VV]; bhn = bhh[n + 2 * VV];
        pdr = pd[n]; pdz = pd[n + VV]; pdn = pd[n + 2 * VV];
        prr_ = pr[n]; prz = pr[n + VV]; prn = pr[n + 2 * VV];
        bir = bih[n]; biz = bih[n + VV]; bin_ = bih[n + 2 * VV];
    }
    __syncthreads();

    float* hp = h_out + (size_t)b * TT * VV;
    const float* hist_f = (const float*)hist;

    for (int t = 0; t < TT; ++t) {
        // ---- matvec: partial dot over k chunk, SGPR broadcast ----
        float4 hv = *(const float4*)&h_lds[k0 + 4 * (l & 7)];
        float a0 = 0.f, a1 = 0.f, a2 = 0.f;
        #pragma unroll
        for (int q = 0; q < 8; ++q) {
            float s0 = bcast(hv.x, q);
            float s1 = bcast(hv.y, q);
            float s2 = bcast(hv.z, q);
            float s3 = bcast(hv.w, q);
            a0 = fmaf(s0, w0[4 * q], a0);     a1 = fmaf(s0, w1[4 * q], a1);     a2 = fmaf(s0, w2[4 * q], a2);
            a0 = fmaf(s1, w0[4 * q + 1], a0); a1 = fmaf(s1, w1[4 * q + 1], a1); a2 = fmaf(s1, w2[4 * q + 1], a2);
            a0 = fmaf(s2, w0[4 * q + 2], a0); a1 = fmaf(s2, w1[4 * q + 2], a1); a2 = fmaf(s2, w2[4 * q + 2], a2);
            a0 = fmaf(s3, w0[4 * q + 3], a0); a1 = fmaf(s3, w1[4 * q + 3], a1); a2 = fmaf(s3, w2[4 * q + 3], a2);
        }
        P[kg][j0] = a0;
        P[kg][j0 + 64] = a1;
        P[kg][j0 + 128] = a2;
        __syncthreads();

        // ---- gates on threads <128; history flush on the rest ----
        if (tid < VV) {
            int n = tid;
            float ghr = P[0][n] + P[1][n] + P[2][n] + P[3][n] + bhr;
            float ghz = P[0][n + 128] + P[1][n + 128] + P[2][n + 128] + P[3][n + 128] + bhz;
            float ghn = P[0][n + 256] + P[1][n + 256] + P[2][n + 256] + P[3][n + 256] + bhn;
            float g = gam_row[t], rr = r_row[t];
            float r = sigm(fmaf(g, pdr, fmaf(rr, prr_, bir)) + ghr);
            float z = sigm(fmaf(g, pdz, fmaf(rr, prz, biz)) + ghz);
            float nn = tanh_f(fmaf(g, pdn, fmaf(rr, prn, bin_)) + r * ghn);
            float h = h_lds[n];
            float hn = fmaf(1.f - z, nn, z * h);
            h_lds[n] = hn;
            hist[t & 7][n] = hn;
        } else if ((t & 7) == 0 && t > 0) {
            int t0 = t - 8;
            for (int i = tid - 128; i < 8 * VV; i += 384)
                hp[t0 * VV + i] = hist_f[i];
        }
        __syncthreads();
    }
    // final 8 steps (t = 192..199)
    for (int i = tid; i < 8 * VV; i += 512)
        hp[192 * VV + i] = hist_f[i];
}

// ---------------- alpha head: bf16 MFMA, fragments loaded straight from global -
__device__ __forceinline__ short f2bf(float f) {
    uint32_t u = __float_as_uint(f);
    u = (u + 0x7FFFu + ((u >> 16) & 1u)) >> 16;
    return (short)u;
}
__device__ __forceinline__ bf16x8 load_cvt8(const float* p) {
    float4 a = *(const float4*)p;
    float4 c = *(const float4*)(p + 4);
    bf16x8 r;
    r[0] = f2bf(a.x); r[1] = f2bf(a.y); r[2] = f2bf(a.z); r[3] = f2bf(a.w);
    r[4] = f2bf(c.x); r[5] = f2bf(c.y); r[6] = f2bf(c.z); r[7] = f2bf(c.w);
    return r;
}

__global__ void alpha_kernel(const float* __restrict__ h_seq, const float* __restrict__ W1a,
                             const float* __restrict__ b1a, const float* __restrict__ W1b,
                             const float* __restrict__ b1b, float* __restrict__ alpha)
{
    int wave = threadIdx.x >> 6;
    int lane = threadIdx.x & 63;
    int tile = blockIdx.x * 4 + wave;  // 800 tiles of 16 rows
    int rowbase = tile * 16;
    int rl = lane & 15, g = lane >> 4;
    const float* hp = h_seq + (size_t)(rowbase + rl) * VV + g * 8;
    bf16x8 a0 = load_cvt8(hp);
    bf16x8 a1 = load_cvt8(hp + 32);
    bf16x8 a2 = load_cvt8(hp + 64);
    bf16x8 a3 = load_cvt8(hp + 96);
    float p0 = 0.f, p1 = 0.f, p2 = 0.f, p3 = 0.f;
    float bb = b1b[0];
    #pragma unroll
    for (int jt = 0; jt < 8; ++jt) {
        int j = jt * 16 + rl;
        const float* wp = W1a + (size_t)j * VV + g * 8;
        f32x4 acc = {0.f, 0.f, 0.f, 0.f};
        acc = __builtin_amdgcn_mfma_f32_16x16x32_bf16(a0, load_cvt8(wp), acc, 0, 0, 0);
        acc = __builtin_amdgcn_mfma_f32_16x16x32_bf16(a1, load_cvt8(wp + 32), acc, 0, 0, 0);
        acc = __builtin_amdgcn_mfma_f32_16x16x32_bf16(a2, load_cvt8(wp + 64), acc, 0, 0, 0);
        acc = __builtin_amdgcn_mfma_f32_16x16x32_bf16(a3, load_cvt8(wp + 96), acc, 0, 0, 0);
        float bj = b1a[j], wj = W1b[j];
        p0 += fmaxf(acc[0] + bj, 0.f) * wj;
        p1 += fmaxf(acc[1] + bj, 0.f) * wj;
        p2 += fmaxf(acc[2] + bj, 0.f) * wj;
        p3 += fmaxf(acc[3] + bj, 0.f) * wj;
    }
    #pragma unroll
    for (int m = 1; m < 16; m <<= 1) {
        p0 += __shfl_xor(p0, m);
        p1 += __shfl_xor(p1, m);
        p2 += __shfl_xor(p2, m);
        p3 += __shfl_xor(p3, m);
    }
    if (rl == 0) {
        alpha[rowbase + g * 4 + 0] = p0 + bb;
        alpha[rowbase + g * 4 + 1] = p1 + bb;
        alpha[rowbase + g * 4 + 2] = p2 + bb;
        alpha[rowbase + g * 4 + 3] = p3 + bb;
    }
}

extern "C" void kernel_launch(void* const* d_in, const int* in_sizes, int n_in,
                              void* d_out, int out_size, void* d_ws, size_t ws_size,
                              hipStream_t stream)
{
    const int*   c_seq = (const int*)d_in[0];
    const int*   d_seq = (const int*)d_in[1];
    const float* r_seq = (const float*)d_in[2];
    const float* D_emb = (const float*)d_in[3];
    const float* v_d   = (const float*)d_in[4];
    const float* v_r   = (const float*)d_in[5];
    const float* v_c   = (const float*)d_in[6];
    const float* W_ih  = (const float*)d_in[7];
    const float* W_hh  = (const float*)d_in[8];
    const float* b_ih  = (const float*)d_in[9];
    const float* b_hh  = (const float*)d_in[10];
    const float* W1a   = (const float*)d_in[11];
    const float* b1a   = (const float*)d_in[12];
    const float* W1b   = (const float*)d_in[13];
    const float* b1b   = (const float*)d_in[14];
    const float* W2a   = (const float*)d_in[15];
    const float* b2a   = (const float*)d_in[16];
    const float* W2b   = (const float*)d_in[17];
    const float* b2b   = (const float*)d_in[18];

    float* out   = (float*)d_out;
    float* alpha = out;                       // 12800
    float* h_seq = out + 12800;               // 1,638,400
    float* C_out = out + 12800 + 1638400;     // 25,600,000
    float* ws    = (float*)d_ws;
    float* newc  = ws + 13952;

    hipLaunchKernelGGL(pre_kernel, dim3(64), dim3(256), 0, stream,
                       d_seq, D_emb, v_d, v_r, v_c, W_ih, W2a, ws);
    hipLaunchKernelGGL(mem_kernel, dim3(BB), dim3(64), 0, stream,
                       c_seq, r_seq, W2b, b2a, b2b, ws, newc);
    hipLaunchKernelGGL(fill_kernel, dim3(BB * 8), dim3(256), 0, stream,
                       c_seq, newc, C_out);
    hipLaunchKernelGGL(gru_kernel, dim3(BB), dim3(512), 0, stream,
                       r_seq, W_hh, b_ih, b_hh, ws, h_seq);
    hipLaunchKernelGGL(alpha_kernel, dim3(200), dim3(256), 0, stream,
                       h_seq, W1a, b1a, W1b, b1b, alpha);
}

// Round 5
// 244.581 us; speedup vs baseline: 1.4043x; 1.1694x over previous
//
#include <hip/hip_runtime.h>
#include <hip/hip_bf16.h>
#include <cstdint>

#define BB 64
#define TT 200
#define KN 2000
#define VV 128

typedef __attribute__((ext_vector_type(8))) short bf16x8;
typedef __attribute__((ext_vector_type(4))) float f32x4;
typedef __attribute__((ext_vector_type(16))) float f32x16;

// ws layout (floats): pd[384]@0, pr[384]@384, uc[128]@768, ud[128]@896,
// ur[128]@1024, newc[12800]@1152   (total 13952 floats)

__device__ __forceinline__ float sigm(float x) { return 1.f / (1.f + __expf(-x)); }
__device__ __forceinline__ float tanh_f(float x) {
    float e = __expf(2.f * x);
    return (e - 1.f) / (e + 1.f);
}
__device__ __forceinline__ float bcast(float v, int lane) {
    return __int_as_float(__builtin_amdgcn_readlane(__float_as_int(v), lane));
}

// ---------------- precompute: small projection vectors ----------
__global__ void pre_kernel(const float* __restrict__ v_d, const float* __restrict__ v_r,
                           const float* __restrict__ v_c, const float* __restrict__ W_ih,
                           const float* __restrict__ W2a, float* __restrict__ ws)
{
    int g = blockIdx.x * 256 + threadIdx.x;   // grid 2 x 256 = 512 threads
    float* pd = ws;
    float* pr = ws + 384;
    float* uc = ws + 768;
    float* ud = ws + 896;
    float* ur = ws + 1024;
    if (g < 384) {
        float a = 0.f, b = 0.f;
        for (int k = 0; k < VV; ++k) {
            a = fmaf(W_ih[g * 256 + k], v_d[k], a);
            b = fmaf(W_ih[g * 256 + VV + k], v_r[k], b);
        }
        pd[g] = a; pr[g] = b;
    }
    if (g < VV) {
        float a = 0.f, b = 0.f, c = 0.f;
        for (int k = 0; k < VV; ++k) {
            a = fmaf(W2a[g * 384 + k], v_c[k], a);
            b = fmaf(W2a[g * 384 + VV + k], v_d[k], b);
            c = fmaf(W2a[g * 384 + 2 * VV + k], v_r[k], c);
        }
        uc[g] = a; ud[g] = b; ur[g] = c;
    }
}

// ---------------- fused: blocks 0-63 GRU scan, blocks 64-127 memory scan -------
// GRU: 1024 threads = 16 waves. wave w: jg=w>>3 (j-base jg*192), kg=w&7 (k0=kg*16).
// Lane l owns outputs j0=jg*192+l, +64, +128 over a 16-wide k chunk; 48 weight
// floats/thread in f32x16 registers (fits VGPR cap 128 from launch_bounds(1024,4)
// -- r4 lesson: 96 floats @ 512thr got demoted to per-step global re-loads, VGPR=68).
// h broadcast: 1 ds_read_b128/wave + v_readlane SGPR broadcast into v_fmac.
// hist[16] slots so the flush (slots t-8..t-1) never collides with the gate
// write (slot t&15) in the same barrier interval.
__global__ __launch_bounds__(1024, 4) void fused_kernel(
    const int* __restrict__ c_seq, const int* __restrict__ d_seq,
    const float* __restrict__ r_seq, const float* __restrict__ D_emb,
    const float* __restrict__ Whh, const float* __restrict__ bih,
    const float* __restrict__ bhh, const float* __restrict__ W2b,
    const float* __restrict__ b2a, const float* __restrict__ b2b,
    const float* __restrict__ ws, float* __restrict__ newc_out,
    float* __restrict__ h_out)
{
    __shared__ __align__(16) float h_lds[VV];
    __shared__ float P[8][384];
    __shared__ __align__(16) float hist[16][VV];
    __shared__ float gam_row[TT], r_row[TT];
    __shared__ float C[KN];
    __shared__ int c_row[TT];

    int tid = threadIdx.x;

    if (blockIdx.x < BB) {
        // ================= GRU path =================
        int b = blockIdx.x;
        const float* pd = ws;
        const float* pr = ws + 384;
        int wid = tid >> 6, l = tid & 63;
        int jg = wid >> 3, kg = wid & 7;
        int j0 = jg * 192 + l;
        int k0 = kg * 16;

        if (tid < TT) {
            gam_row[tid] = D_emb[d_seq[b * TT + tid]];
            r_row[tid] = r_seq[b * TT + tid];
        }
        if (tid < VV) h_lds[tid] = 0.f;

        // 48 weight floats per thread, in vector registers
        f32x16 w0, w1, w2;
        #pragma unroll
        for (int q = 0; q < 4; ++q) {
            float4 a = *(const float4*)(Whh + (size_t)j0 * VV + k0 + 4 * q);
            float4 c = *(const float4*)(Whh + (size_t)(j0 + 64) * VV + k0 + 4 * q);
            float4 d = *(const float4*)(Whh + (size_t)(j0 + 128) * VV + k0 + 4 * q);
            w0[4 * q] = a.x; w0[4 * q + 1] = a.y; w0[4 * q + 2] = a.z; w0[4 * q + 3] = a.w;
            w1[4 * q] = c.x; w1[4 * q + 1] = c.y; w1[4 * q + 2] = c.z; w1[4 * q + 3] = c.w;
            w2[4 * q] = d.x; w2[4 * q + 1] = d.y; w2[4 * q + 2] = d.z; w2[4 * q + 3] = d.w;
        }

        // gate-thread preloads (tid < 128)
        float bhr = 0.f, bhz = 0.f, bhn = 0.f;
        float pdr = 0.f, pdz = 0.f, pdn = 0.f, prr_ = 0.f, prz = 0.f, prn = 0.f;
        float bir = 0.f, biz = 0.f, bin_ = 0.f;
        if (tid < VV) {
            int n = tid;
            bhr = bhh[n]; bhz = bhh[n + VV]; bhn = bhh[n + 2 * VV];
            pdr = pd[n]; pdz = pd[n + VV]; pdn = pd[n + 2 * VV];
            prr_ = pr[n]; prz = pr[n + VV]; prn = pr[n + 2 * VV];
            bir = bih[n]; biz = bih[n + VV]; bin_ = bih[n + 2 * VV];
        }
        __syncthreads();

        float* hp = h_out + (size_t)b * TT * VV;
        const float* hist_f = (const float*)hist;
        const float* hvp = &h_lds[k0 + 4 * (l & 3)];

        for (int t = 0; t < TT; ++t) {
            // ---- matvec: 16-wide k chunk, SGPR broadcast ----
            float4 hv = *(const float4*)hvp;
            float a0 = 0.f, a1 = 0.f, a2 = 0.f;
            #pragma unroll
            for (int q = 0; q < 4; ++q) {
                float s0 = bcast(hv.x, q);
                float s1 = bcast(hv.y, q);
                float s2 = bcast(hv.z, q);
                float s3 = bcast(hv.w, q);
                a0 = fmaf(s0, w0[4 * q], a0);     a1 = fmaf(s0, w1[4 * q], a1);     a2 = fmaf(s0, w2[4 * q], a2);
                a0 = fmaf(s1, w0[4 * q + 1], a0); a1 = fmaf(s1, w1[4 * q + 1], a1); a2 = fmaf(s1, w2[4 * q + 1], a2);
                a0 = fmaf(s2, w0[4 * q + 2], a0); a1 = fmaf(s2, w1[4 * q + 2], a1); a2 = fmaf(s2, w2[4 * q + 2], a2);
                a0 = fmaf(s3, w0[4 * q + 3], a0); a1 = fmaf(s3, w1[4 * q + 3], a1); a2 = fmaf(s3, w2[4 * q + 3], a2);
            }
            P[kg][j0] = a0;
            P[kg][j0 + 64] = a1;
            P[kg][j0 + 128] = a2;
            __syncthreads();

            // ---- gates on threads <128; history flush on the rest ----
            if (tid < VV) {
                int n = tid;
                float ghr = ((P[0][n] + P[1][n]) + (P[2][n] + P[3][n]))
                          + ((P[4][n] + P[5][n]) + (P[6][n] + P[7][n])) + bhr;
                int nz = n + 128;
                float ghz = ((P[0][nz] + P[1][nz]) + (P[2][nz] + P[3][nz]))
                          + ((P[4][nz] + P[5][nz]) + (P[6][nz] + P[7][nz])) + bhz;
                int nn2 = n + 256;
                float ghn = ((P[0][nn2] + P[1][nn2]) + (P[2][nn2] + P[3][nn2]))
                          + ((P[4][nn2] + P[5][nn2]) + (P[6][nn2] + P[7][nn2])) + bhn;
                float g = gam_row[t], rr = r_row[t];
                float r = sigm(fmaf(g, pdr, fmaf(rr, prr_, bir)) + ghr);
                float z = sigm(fmaf(g, pdz, fmaf(rr, prz, biz)) + ghz);
                float nn = tanh_f(fmaf(g, pdn, fmaf(rr, prn, bin_)) + r * ghn);
                float h = h_lds[n];
                float hn = fmaf(1.f - z, nn, z * h);
                h_lds[n] = hn;
                hist[t & 15][n] = hn;
            } else if ((t & 7) == 0 && t > 0) {
                int t0 = t - 8;                     // flush slots (t-8..t-1)&15
                int s0 = t0 & 15;                   // contiguous 8-slot group
                for (int i = tid - 128; i < 8 * VV; i += 896)
                    hp[t0 * VV + i] = hist_f[s0 * VV + i];
            }
            __syncthreads();
        }
        // final 8 steps (t = 192..199 -> slots 0..7)
        for (int i = tid; i < 8 * VV; i += 1024)
            hp[192 * VV + i] = hist_f[i];
    } else {
        // ================= memory-scan path =================
        int b = blockIdx.x - BB;
        const float* uc = ws + 768;
        const float* ud = ws + 896;
        const float* ur = ws + 1024;
        for (int i = tid; i < KN; i += 1024) C[i] = 0.f;
        if (tid < TT) {
            gam_row[tid] = D_emb[d_seq[b * TT + tid]];
            r_row[tid] = r_seq[b * TT + tid];
            c_row[tid] = c_seq[b * TT + tid];
        }
        __syncthreads();
        if (tid >= 64) return;
        int l = tid;
        float uc0 = uc[l], uc1 = uc[l + 64];
        float ud0 = ud[l], ud1 = ud[l + 64];
        float ur0 = ur[l], ur1 = ur[l + 64];
        float ba0 = b2a[l], ba1 = b2a[l + 64];
        float wb0 = W2b[l], wb1 = W2b[l + 64];
        float bb = b2b[0];
        for (int t = 0; t < TT; ++t) {
            int ct = c_row[t];
            float beta = C[ct];
            float g = gam_row[t], rr = r_row[t];
            float h0 = fmaxf(fmaf(beta, uc0, fmaf(g, ud0, fmaf(rr, ur0, ba0))), 0.f);
            float h1 = fmaxf(fmaf(beta, uc1, fmaf(g, ud1, fmaf(rr, ur1, ba1))), 0.f);
            float p = fmaf(h0, wb0, h1 * wb1);
            #pragma unroll
            for (int m = 32; m > 0; m >>= 1) p += __shfl_xor(p, m);
            float nc = p + bb;
            if (l == 0) {
                C[ct] = nc;
                newc_out[b * TT + t] = nc;
            }
        }
    }
}

// ---------------- C_seq fill: parallel reconstruction, coalesced in k ----------
__global__ void fill_kernel(const int* __restrict__ c_seq, const float* __restrict__ newc,
                            float* __restrict__ C_out)
{
    int b = blockIdx.x >> 3;
    int kc = blockIdx.x & 7;
    int k = kc * 256 + threadIdx.x;
    __shared__ int c_row[TT];
    __shared__ float n_row[TT];
    for (int i = threadIdx.x; i < TT; i += 256) {
        c_row[i] = c_seq[b * TT + i];
        n_row[i] = newc[b * TT + i];
    }
    __syncthreads();
    if (k >= KN) return;
    float cur = 0.f;
    float* outp = C_out + (size_t)b * TT * KN + k;
    for (int t = 0; t < TT; ++t) {
        if (c_row[t] == k) cur = n_row[t];
        outp[(size_t)t * KN] = cur;
    }
}

// ---------------- alpha head: bf16 MFMA, fragments loaded straight from global -
__device__ __forceinline__ short f2bf(float f) {
    uint32_t u = __float_as_uint(f);
    u = (u + 0x7FFFu + ((u >> 16) & 1u)) >> 16;
    return (short)u;
}
__device__ __forceinline__ bf16x8 load_cvt8(const float* p) {
    float4 a = *(const float4*)p;
    float4 c = *(const float4*)(p + 4);
    bf16x8 r;
    r[0] = f2bf(a.x); r[1] = f2bf(a.y); r[2] = f2bf(a.z); r[3] = f2bf(a.w);
    r[4] = f2bf(c.x); r[5] = f2bf(c.y); r[6] = f2bf(c.z); r[7] = f2bf(c.w);
    return r;
}

__global__ void alpha_kernel(const float* __restrict__ h_seq, const float* __restrict__ W1a,
                             const float* __restrict__ b1a, const float* __restrict__ W1b,
                             const float* __restrict__ b1b, float* __restrict__ alpha)
{
    int wave = threadIdx.x >> 6;
    int lane = threadIdx.x & 63;
    int tile = blockIdx.x * 4 + wave;  // 800 tiles of 16 rows
    int rowbase = tile * 16;
    int rl = lane & 15, g = lane >> 4;
    const float* hp = h_seq + (size_t)(rowbase + rl) * VV + g * 8;
    bf16x8 a0 = load_cvt8(hp);
    bf16x8 a1 = load_cvt8(hp + 32);
    bf16x8 a2 = load_cvt8(hp + 64);
    bf16x8 a3 = load_cvt8(hp + 96);
    float p0 = 0.f, p1 = 0.f, p2 = 0.f, p3 = 0.f;
    float bb = b1b[0];
    #pragma unroll
    for (int jt = 0; jt < 8; ++jt) {
        int j = jt * 16 + rl;
        const float* wp = W1a + (size_t)j * VV + g * 8;
        f32x4 acc = {0.f, 0.f, 0.f, 0.f};
        acc = __builtin_amdgcn_mfma_f32_16x16x32_bf16(a0, load_cvt8(wp), acc, 0, 0, 0);
        acc = __builtin_amdgcn_mfma_f32_16x16x32_bf16(a1, load_cvt8(wp + 32), acc, 0, 0, 0);
        acc = __builtin_amdgcn_mfma_f32_16x16x32_bf16(a2, load_cvt8(wp + 64), acc, 0, 0, 0);
        acc = __builtin_amdgcn_mfma_f32_16x16x32_bf16(a3, load_cvt8(wp + 96), acc, 0, 0, 0);
        float bj = b1a[j], wj = W1b[j];
        p0 += fmaxf(acc[0] + bj, 0.f) * wj;
        p1 += fmaxf(acc[1] + bj, 0.f) * wj;
        p2 += fmaxf(acc[2] + bj, 0.f) * wj;
        p3 += fmaxf(acc[3] + bj, 0.f) * wj;
    }
    #pragma unroll
    for (int m = 1; m < 16; m <<= 1) {
        p0 += __shfl_xor(p0, m);
        p1 += __shfl_xor(p1, m);
        p2 += __shfl_xor(p2, m);
        p3 += __shfl_xor(p3, m);
    }
    if (rl == 0) {
        alpha[rowbase + g * 4 + 0] = p0 + bb;
        alpha[rowbase + g * 4 + 1] = p1 + bb;
        alpha[rowbase + g * 4 + 2] = p2 + bb;
        alpha[rowbase + g * 4 + 3] = p3 + bb;
    }
}

extern "C" void kernel_launch(void* const* d_in, const int* in_sizes, int n_in,
                              void* d_out, int out_size, void* d_ws, size_t ws_size,
                              hipStream_t stream)
{
    const int*   c_seq = (const int*)d_in[0];
    const int*   d_seq = (const int*)d_in[1];
    const float* r_seq = (const float*)d_in[2];
    const float* D_emb = (const float*)d_in[3];
    const float* v_d   = (const float*)d_in[4];
    const float* v_r   = (const float*)d_in[5];
    const float* v_c   = (const float*)d_in[6];
    const float* W_ih  = (const float*)d_in[7];
    const float* W_hh  = (const float*)d_in[8];
    const float* b_ih  = (const float*)d_in[9];
    const float* b_hh  = (const float*)d_in[10];
    const float* W1a   = (const float*)d_in[11];
    const float* b1a   = (const float*)d_in[12];
    const float* W1b   = (const float*)d_in[13];
    const float* b1b   = (const float*)d_in[14];
    const float* W2a   = (const float*)d_in[15];
    const float* b2a   = (const float*)d_in[16];
    const float* W2b   = (const float*)d_in[17];
    const float* b2b   = (const float*)d_in[18];

    float* out   = (float*)d_out;
    float* alpha = out;                       // 12800
    float* h_seq = out + 12800;               // 1,638,400
    float* C_out = out + 12800 + 1638400;     // 25,600,000
    float* ws    = (float*)d_ws;
    float* newc  = ws + 1152;

    hipLaunchKernelGGL(pre_kernel, dim3(2), dim3(256), 0, stream,
                       v_d, v_r, v_c, W_ih, W2a, ws);
    hipLaunchKernelGGL(fused_kernel, dim3(BB * 2), dim3(1024), 0, stream,
                       c_seq, d_seq, r_seq, D_emb, W_hh, b_ih, b_hh,
                       W2b, b2a, b2b, ws, newc, h_seq);
    hipLaunchKernelGGL(fill_kernel, dim3(BB * 8), dim3(256), 0, stream,
                       c_seq, newc, C_out);
    hipLaunchKernelGGL(alpha_kernel, dim3(200), dim3(256), 0, stream,
                       h_seq, W1a, b1a, W1b, b1b, alpha);
}

// Round 6
// 230.334 us; speedup vs baseline: 1.4911x; 1.0619x over previous
//
#include <hip/hip_runtime.h>
#include <hip/hip_bf16.h>
#include <cstdint>

#define BB 64
#define TT 200
#define KN 2000
#define VV 128

typedef __attribute__((ext_vector_type(8))) short bf16x8;
typedef __attribute__((ext_vector_type(4))) float f32x4;
typedef __attribute__((ext_vector_type(16))) float f32x16;

// ws layout (floats): pd[384]@0, pr[384]@384, uc[128]@768, ud[128]@896, ur[128]@1024

__device__ __forceinline__ float sigm(float x) { return 1.f / (1.f + __expf(-x)); }
__device__ __forceinline__ float tanh_f(float x) {
    float e = __expf(2.f * x);
    return (e - 1.f) / (e + 1.f);
}
__device__ __forceinline__ float bcast(float v, int lane) {
    return __int_as_float(__builtin_amdgcn_readlane(__float_as_int(v), lane));
}

// ---------------- precompute: small projection vectors ----------
__global__ void pre_kernel(const float* __restrict__ v_d, const float* __restrict__ v_r,
                           const float* __restrict__ v_c, const float* __restrict__ W_ih,
                           const float* __restrict__ W2a, float* __restrict__ ws)
{
    int g = blockIdx.x * 256 + threadIdx.x;   // grid 2 x 256 = 512 threads
    float* pd = ws;
    float* pr = ws + 384;
    float* uc = ws + 768;
    float* ud = ws + 896;
    float* ur = ws + 1024;
    if (g < 384) {
        float a = 0.f, b = 0.f;
        for (int k = 0; k < VV; ++k) {
            a = fmaf(W_ih[g * 256 + k], v_d[k], a);
            b = fmaf(W_ih[g * 256 + VV + k], v_r[k], b);
        }
        pd[g] = a; pr[g] = b;
    }
    if (g < VV) {
        float a = 0.f, b = 0.f, c = 0.f;
        for (int k = 0; k < VV; ++k) {
            a = fmaf(W2a[g * 384 + k], v_c[k], a);
            b = fmaf(W2a[g * 384 + VV + k], v_d[k], b);
            c = fmaf(W2a[g * 384 + 2 * VV + k], v_r[k], c);
        }
        uc[g] = a; ud[g] = b; ur[g] = c;
    }
}

// ---------------- fused: blocks 0-63 GRU scan, blocks 64-127 memory scan + C_out
// GRU: 1024 threads = 16 waves. wave w: jg=w>>3 (j-base jg*192), kg=w&7 (k0=kg*16).
// Lane l owns outputs j0=jg*192+l, +64, +128 over a 16-wide k chunk; 48 weight
// floats/thread in f32x16 registers, PINNED via loop-carried "+v" asm (r5 lesson:
// without the pin, hipcc sinks the Whh loads into the t-loop; VGPR_Count=44 and
// the matvec re-streams weights from L2 every step).
// Mem path: single wave scans C and streams the full 2000-float row to C_out[b][t]
// each step (replaces the separate fill_kernel; no cross-wave race possible).
__global__ __launch_bounds__(1024, 4) void fused_kernel(
    const int* __restrict__ c_seq, const int* __restrict__ d_seq,
    const float* __restrict__ r_seq, const float* __restrict__ D_emb,
    const float* __restrict__ Whh, const float* __restrict__ bih,
    const float* __restrict__ bhh, const float* __restrict__ W2b,
    const float* __restrict__ b2a, const float* __restrict__ b2b,
    const float* __restrict__ ws, float* __restrict__ C_out,
    float* __restrict__ h_out)
{
    __shared__ __align__(16) float h_lds[VV];
    __shared__ float P[8][384];
    __shared__ __align__(16) float hist[16][VV];
    __shared__ float gam_row[TT], r_row[TT];
    __shared__ __align__(16) float C[KN];
    __shared__ int c_row[TT];

    int tid = threadIdx.x;

    if (blockIdx.x < BB) {
        // ================= GRU path =================
        int b = blockIdx.x;
        const float* pd = ws;
        const float* pr = ws + 384;
        int wid = tid >> 6, l = tid & 63;
        int jg = wid >> 3, kg = wid & 7;
        int j0 = jg * 192 + l;
        int k0 = kg * 16;

        if (tid < TT) {
            gam_row[tid] = D_emb[d_seq[b * TT + tid]];
            r_row[tid] = r_seq[b * TT + tid];
        }
        if (tid < VV) h_lds[tid] = 0.f;

        // 48 weight floats per thread, in vector registers
        f32x16 w0, w1, w2;
        #pragma unroll
        for (int q = 0; q < 4; ++q) {
            float4 a = *(const float4*)(Whh + (size_t)j0 * VV + k0 + 4 * q);
            float4 c = *(const float4*)(Whh + (size_t)(j0 + 64) * VV + k0 + 4 * q);
            float4 d = *(const float4*)(Whh + (size_t)(j0 + 128) * VV + k0 + 4 * q);
            w0[4 * q] = a.x; w0[4 * q + 1] = a.y; w0[4 * q + 2] = a.z; w0[4 * q + 3] = a.w;
            w1[4 * q] = c.x; w1[4 * q + 1] = c.y; w1[4 * q + 2] = c.z; w1[4 * q + 3] = c.w;
            w2[4 * q] = d.x; w2[4 * q + 1] = d.y; w2[4 * q + 2] = d.z; w2[4 * q + 3] = d.w;
        }

        // gate-thread preloads (tid < 128)
        float bhr = 0.f, bhz = 0.f, bhn = 0.f;
        float pdr = 0.f, pdz = 0.f, pdn = 0.f, prr_ = 0.f, prz = 0.f, prn = 0.f;
        float bir = 0.f, biz = 0.f, bin_ = 0.f;
        if (tid < VV) {
            int n = tid;
            bhr = bhh[n]; bhz = bhh[n + VV]; bhn = bhh[n + 2 * VV];
            pdr = pd[n]; pdz = pd[n + VV]; pdn = pd[n + 2 * VV];
            prr_ = pr[n]; prz = pr[n + VV]; prn = pr[n + 2 * VV];
            bir = bih[n]; biz = bih[n + VV]; bin_ = bih[n + 2 * VV];
        }
        __syncthreads();

        float* hp = h_out + (size_t)b * TT * VV;
        const float* hist_f = (const float*)hist;
        const float* hvp = &h_lds[k0 + 4 * (l & 3)];

        for (int t = 0; t < TT; ++t) {
            // pin weights in VGPRs: loop-carried fake-modify forbids remat-from-memory
            asm volatile("" : "+v"(w0), "+v"(w1), "+v"(w2));
            // ---- matvec: 16-wide k chunk, SGPR broadcast ----
            float4 hv = *(const float4*)hvp;
            float a0 = 0.f, a1 = 0.f, a2 = 0.f;
            #pragma unroll
            for (int q = 0; q < 4; ++q) {
                float s0 = bcast(hv.x, q);
                float s1 = bcast(hv.y, q);
                float s2 = bcast(hv.z, q);
                float s3 = bcast(hv.w, q);
                a0 = fmaf(s0, w0[4 * q], a0);     a1 = fmaf(s0, w1[4 * q], a1);     a2 = fmaf(s0, w2[4 * q], a2);
                a0 = fmaf(s1, w0[4 * q + 1], a0); a1 = fmaf(s1, w1[4 * q + 1], a1); a2 = fmaf(s1, w2[4 * q + 1], a2);
                a0 = fmaf(s2, w0[4 * q + 2], a0); a1 = fmaf(s2, w1[4 * q + 2], a1); a2 = fmaf(s2, w2[4 * q + 2], a2);
                a0 = fmaf(s3, w0[4 * q + 3], a0); a1 = fmaf(s3, w1[4 * q + 3], a1); a2 = fmaf(s3, w2[4 * q + 3], a2);
            }
            P[kg][j0] = a0;
            P[kg][j0 + 64] = a1;
            P[kg][j0 + 128] = a2;
            __syncthreads();

            // ---- gates on threads <128; history flush on the rest ----
            if (tid < VV) {
                int n = tid;
                float ghr = ((P[0][n] + P[1][n]) + (P[2][n] + P[3][n]))
                          + ((P[4][n] + P[5][n]) + (P[6][n] + P[7][n])) + bhr;
                int nz = n + 128;
                float ghz = ((P[0][nz] + P[1][nz]) + (P[2][nz] + P[3][nz]))
                          + ((P[4][nz] + P[5][nz]) + (P[6][nz] + P[7][nz])) + bhz;
                int nn2 = n + 256;
                float ghn = ((P[0][nn2] + P[1][nn2]) + (P[2][nn2] + P[3][nn2]))
                          + ((P[4][nn2] + P[5][nn2]) + (P[6][nn2] + P[7][nn2])) + bhn;
                float g = gam_row[t], rr = r_row[t];
                float r = sigm(fmaf(g, pdr, fmaf(rr, prr_, bir)) + ghr);
                float z = sigm(fmaf(g, pdz, fmaf(rr, prz, biz)) + ghz);
                float nn = tanh_f(fmaf(g, pdn, fmaf(rr, prn, bin_)) + r * ghn);
                float h = h_lds[n];
                float hn = fmaf(1.f - z, nn, z * h);
                h_lds[n] = hn;
                hist[t & 15][n] = hn;
            } else if ((t & 7) == 0 && t > 0) {
                int t0 = t - 8;                     // flush slots (t-8..t-1)&15
                int s0 = t0 & 15;                   // contiguous 8-slot group
                for (int i = tid - 128; i < 8 * VV; i += 896)
                    hp[t0 * VV + i] = hist_f[s0 * VV + i];
            }
            __syncthreads();
        }
        // final 8 steps (t = 192..199 -> slots 0..7)
        for (int i = tid; i < 8 * VV; i += 1024)
            hp[192 * VV + i] = hist_f[i];
    } else {
        // ================= memory-scan path (single wave) =================
        int b = blockIdx.x - BB;
        const float* uc = ws + 768;
        const float* ud = ws + 896;
        const float* ur = ws + 1024;
        for (int i = tid; i < KN; i += 1024) C[i] = 0.f;
        if (tid < TT) {
            gam_row[tid] = D_emb[d_seq[b * TT + tid]];
            r_row[tid] = r_seq[b * TT + tid];
            c_row[tid] = c_seq[b * TT + tid];
        }
        __syncthreads();
        if (tid >= 64) return;
        int l = tid;
        float uc0 = uc[l], uc1 = uc[l + 64];
        float ud0 = ud[l], ud1 = ud[l + 64];
        float ur0 = ur[l], ur1 = ur[l + 64];
        float ba0 = b2a[l], ba1 = b2a[l + 64];
        float wb0 = W2b[l], wb1 = W2b[l + 64];
        float bb = b2b[0];
        float* cop = C_out + (size_t)b * TT * KN;
        for (int t = 0; t < TT; ++t) {
            int ct = c_row[t];
            float beta = C[ct];
            float g = gam_row[t], rr = r_row[t];
            float h0 = fmaxf(fmaf(beta, uc0, fmaf(g, ud0, fmaf(rr, ur0, ba0))), 0.f);
            float h1 = fmaxf(fmaf(beta, uc1, fmaf(g, ud1, fmaf(rr, ur1, ba1))), 0.f);
            float p = fmaf(h0, wb0, h1 * wb1);
            #pragma unroll
            for (int m = 32; m > 0; m >>= 1) p += __shfl_xor(p, m);
            float nc = p + bb;
            if (l == 0) C[ct] = nc;
            // stream the updated row to C_out[b][t][:] (lds write above is
            // ordered before these reads by the compiler's lgkmcnt waits;
            // single wave -> no cross-wave race)
            float* rowp = cop + (size_t)t * KN;
            #pragma unroll
            for (int s = 0; s < 8; ++s) {
                int idx = 256 * s + 4 * l;
                if (s < 7 || l < 52) {
                    float4 v = *(const float4*)&C[idx];
                    *(float4*)&rowp[idx] = v;
                }
            }
        }
    }
}

// ---------------- alpha head: bf16 MFMA, fragments loaded straight from global -
__device__ __forceinline__ short f2bf(float f) {
    uint32_t u = __float_as_uint(f);
    u = (u + 0x7FFFu + ((u >> 16) & 1u)) >> 16;
    return (short)u;
}
__device__ __forceinline__ bf16x8 load_cvt8(const float* p) {
    float4 a = *(const float4*)p;
    float4 c = *(const float4*)(p + 4);
    bf16x8 r;
    r[0] = f2bf(a.x); r[1] = f2bf(a.y); r[2] = f2bf(a.z); r[3] = f2bf(a.w);
    r[4] = f2bf(c.x); r[5] = f2bf(c.y); r[6] = f2bf(c.z); r[7] = f2bf(c.w);
    return r;
}

__global__ void alpha_kernel(const float* __restrict__ h_seq, const float* __restrict__ W1a,
                             const float* __restrict__ b1a, const float* __restrict__ W1b,
                             const float* __restrict__ b1b, float* __restrict__ alpha)
{
    int wave = threadIdx.x >> 6;
    int lane = threadIdx.x & 63;
    int tile = blockIdx.x * 4 + wave;  // 800 tiles of 16 rows
    int rowbase = tile * 16;
    int rl = lane & 15, g = lane >> 4;
    const float* hp = h_seq + (size_t)(rowbase + rl) * VV + g * 8;
    bf16x8 a0 = load_cvt8(hp);
    bf16x8 a1 = load_cvt8(hp + 32);
    bf16x8 a2 = load_cvt8(hp + 64);
    bf16x8 a3 = load_cvt8(hp + 96);
    float p0 = 0.f, p1 = 0.f, p2 = 0.f, p3 = 0.f;
    float bb = b1b[0];
    #pragma unroll
    for (int jt = 0; jt < 8; ++jt) {
        int j = jt * 16 + rl;
        const float* wp = W1a + (size_t)j * VV + g * 8;
        f32x4 acc = {0.f, 0.f, 0.f, 0.f};
        acc = __builtin_amdgcn_mfma_f32_16x16x32_bf16(a0, load_cvt8(wp), acc, 0, 0, 0);
        acc = __builtin_amdgcn_mfma_f32_16x16x32_bf16(a1, load_cvt8(wp + 32), acc, 0, 0, 0);
        acc = __builtin_amdgcn_mfma_f32_16x16x32_bf16(a2, load_cvt8(wp + 64), acc, 0, 0, 0);
        acc = __builtin_amdgcn_mfma_f32_16x16x32_bf16(a3, load_cvt8(wp + 96), acc, 0, 0, 0);
        float bj = b1a[j], wj = W1b[j];
        p0 += fmaxf(acc[0] + bj, 0.f) * wj;
        p1 += fmaxf(acc[1] + bj, 0.f) * wj;
        p2 += fmaxf(acc[2] + bj, 0.f) * wj;
        p3 += fmaxf(acc[3] + bj, 0.f) * wj;
    }
    #pragma unroll
    for (int m = 1; m < 16; m <<= 1) {
        p0 += __shfl_xor(p0, m);
        p1 += __shfl_xor(p1, m);
        p2 += __shfl_xor(p2, m);
        p3 += __shfl_xor(p3, m);
    }
    if (rl == 0) {
        alpha[rowbase + g * 4 + 0] = p0 + bb;
        alpha[rowbase + g * 4 + 1] = p1 + bb;
        alpha[rowbase + g * 4 + 2] = p2 + bb;
        alpha[rowbase + g * 4 + 3] = p3 + bb;
    }
}

extern "C" void kernel_launch(void* const* d_in, const int* in_sizes, int n_in,
                              void* d_out, int out_size, void* d_ws, size_t ws_size,
                              hipStream_t stream)
{
    const int*   c_seq = (const int*)d_in[0];
    const int*   d_seq = (const int*)d_in[1];
    const float* r_seq = (const float*)d_in[2];
    const float* D_emb = (const float*)d_in[3];
    const float* v_d   = (const float*)d_in[4];
    const float* v_r   = (const float*)d_in[5];
    const float* v_c   = (const float*)d_in[6];
    const float* W_ih  = (const float*)d_in[7];
    const float* W_hh  = (const float*)d_in[8];
    const float* b_ih  = (const float*)d_in[9];
    const float* b_hh  = (const float*)d_in[10];
    const float* W1a   = (const float*)d_in[11];
    const float* b1a   = (const float*)d_in[12];
    const float* W1b   = (const float*)d_in[13];
    const float* b1b   = (const float*)d_in[14];
    const float* W2a   = (const float*)d_in[15];
    const float* b2a   = (const float*)d_in[16];
    const float* W2b   = (const float*)d_in[17];
    const float* b2b   = (const float*)d_in[18];

    float* out   = (float*)d_out;
    float* alpha = out;                       // 12800
    float* h_seq = out + 12800;               // 1,638,400
    float* C_out = out + 12800 + 1638400;     // 25,600,000
    float* ws    = (float*)d_ws;

    hipLaunchKernelGGL(pre_kernel, dim3(2), dim3(256), 0, stream,
                       v_d, v_r, v_c, W_ih, W2a, ws);
    hipLaunchKernelGGL(fused_kernel, dim3(BB * 2), dim3(1024), 0, stream,
                       c_seq, d_seq, r_seq, D_emb, W_hh, b_ih, b_hh,
                       W2b, b2a, b2b, ws, C_out, h_seq);
    hipLaunchKernelGGL(alpha_kernel, dim3(200), dim3(256), 0, stream,
                       h_seq, W1a, b1a, W1b, b1b, alpha);
}

// Round 7
// 214.071 us; speedup vs baseline: 1.6044x; 1.0760x over previous
//
#include <hip/hip_runtime.h>
#include <hip/hip_bf16.h>
#include <cstdint>

#define BB 64
#define TT 200
#define KN 2000
#define VV 128

typedef __attribute__((ext_vector_type(8))) short bf16x8;
typedef __attribute__((ext_vector_type(4))) float f32x4;
typedef __attribute__((ext_vector_type(16))) float f32x16;

// ws layout (floats): pd[384]@0, pr[384]@384, uc[128]@768, ud[128]@896, ur[128]@1024

__device__ __forceinline__ float sigm(float x) { return 1.f / (1.f + __expf(-x)); }
__device__ __forceinline__ float tanh_f(float x) {
    float e = __expf(2.f * x);
    return (e - 1.f) / (e + 1.f);
}

// ---------------- precompute: small projection vectors ----------
__global__ void pre_kernel(const float* __restrict__ v_d, const float* __restrict__ v_r,
                           const float* __restrict__ v_c, const float* __restrict__ W_ih,
                           const float* __restrict__ W2a, float* __restrict__ ws)
{
    int g = blockIdx.x * 256 + threadIdx.x;   // grid 2 x 256 = 512 threads
    float* pd = ws;
    float* pr = ws + 384;
    float* uc = ws + 768;
    float* ud = ws + 896;
    float* ur = ws + 1024;
    if (g < 384) {
        float a = 0.f, b = 0.f;
        for (int k = 0; k < VV; ++k) {
            a = fmaf(W_ih[g * 256 + k], v_d[k], a);
            b = fmaf(W_ih[g * 256 + VV + k], v_r[k], b);
        }
        pd[g] = a; pr[g] = b;
    }
    if (g < VV) {
        float a = 0.f, b = 0.f, c = 0.f;
        for (int k = 0; k < VV; ++k) {
            a = fmaf(W2a[g * 384 + k], v_c[k], a);
            b = fmaf(W2a[g * 384 + VV + k], v_d[k], b);
            c = fmaf(W2a[g * 384 + 2 * VV + k], v_r[k], c);
        }
        uc[g] = a; ud[g] = b; ur[g] = c;
    }
}

// ---------------- fused: blocks 0-63 GRU scan, blocks 64-127 memory scan + C_out
// GRU: 16 waves, jg=wid>>3 (j-base jg*192), kg=wid&7 (k0=kg*16), 3 j/lane,
// 48 weight floats/thread. h broadcast via UNIFORM-address ds_read_b128 (free
// LDS broadcast -- r6 lesson: v_readlane is VALU and cost 16/wave/step).
// gi (gamma*pd + r*pr + b_ih) and b_hh folded into the kg==2 wave's partials
// for r/z gates; b_hh folded for n-gate (it sits inside the r-multiplied term,
// gi_n added by the gate thread). Gate phase = 8-partial tree-sum + nonlinearity.
__global__ __launch_bounds__(1024, 4) void fused_kernel(
    const int* __restrict__ c_seq, const int* __restrict__ d_seq,
    const float* __restrict__ r_seq, const float* __restrict__ D_emb,
    const float* __restrict__ Whh, const float* __restrict__ bih,
    const float* __restrict__ bhh, const float* __restrict__ W2b,
    const float* __restrict__ b2a, const float* __restrict__ b2b,
    const float* __restrict__ ws, float* __restrict__ C_out,
    float* __restrict__ h_out)
{
    __shared__ __align__(16) float h_lds[VV];
    __shared__ float P[8][384];
    __shared__ __align__(16) float hist[16][VV];
    __shared__ float gam_row[TT], r_row[TT];
    __shared__ __align__(16) float C[KN];
    __shared__ int c_row[TT];

    int tid = threadIdx.x;

    if (blockIdx.x < BB) {
        // ================= GRU path =================
        int b = blockIdx.x;
        const float* pd = ws;
        const float* pr = ws + 384;
        int wid = tid >> 6, l = tid & 63;
        int jg = wid >> 3, kg = wid & 7;
        int j0 = jg * 192 + l;
        int k0 = kg * 16;

        if (tid < TT) {
            gam_row[tid] = D_emb[d_seq[b * TT + tid]];
            r_row[tid] = r_seq[b * TT + tid];
        }
        if (tid < VV) h_lds[tid] = 0.f;

        // 48 weight floats per thread
        f32x16 w0, w1, w2;
        #pragma unroll
        for (int q = 0; q < 4; ++q) {
            float4 a = *(const float4*)(Whh + (size_t)j0 * VV + k0 + 4 * q);
            float4 c = *(const float4*)(Whh + (size_t)(j0 + 64) * VV + k0 + 4 * q);
            float4 d = *(const float4*)(Whh + (size_t)(j0 + 128) * VV + k0 + 4 * q);
            w0[4 * q] = a.x; w0[4 * q + 1] = a.y; w0[4 * q + 2] = a.z; w0[4 * q + 3] = a.w;
            w1[4 * q] = c.x; w1[4 * q + 1] = c.y; w1[4 * q + 2] = c.z; w1[4 * q + 3] = c.w;
            w2[4 * q] = d.x; w2[4 * q + 1] = d.y; w2[4 * q + 2] = d.z; w2[4 * q + 3] = d.w;
        }

        // kg==2 gi/bias fold preloads. slots j0, j0+64, j0+128:
        // jg==0 -> all three < 256 (r/z): full gi+bih+bhh fold.
        // jg==1 -> slot0 in [192,256) full fold; slots 1,2 >= 256 (n): bhh only.
        float apd0 = 0.f, apr0 = 0.f, ab0 = 0.f;
        float apd1 = 0.f, apr1 = 0.f, ab1 = 0.f;
        float apd2 = 0.f, apr2 = 0.f, ab2 = 0.f;
        if (kg == 2) {
            apd0 = pd[j0]; apr0 = pr[j0]; ab0 = bih[j0] + bhh[j0];
            if (jg == 0) {
                apd1 = pd[j0 + 64]; apr1 = pr[j0 + 64]; ab1 = bih[j0 + 64] + bhh[j0 + 64];
                apd2 = pd[j0 + 128]; apr2 = pr[j0 + 128]; ab2 = bih[j0 + 128] + bhh[j0 + 128];
            } else {
                ab1 = bhh[j0 + 64]; ab2 = bhh[j0 + 128];
            }
        }

        // gate-thread preloads (tid < 128): only the n-gate gi terms remain
        float pdn = 0.f, prn = 0.f, bin_ = 0.f;
        if (tid < VV) {
            pdn = pd[tid + 2 * VV]; prn = pr[tid + 2 * VV]; bin_ = bih[tid + 2 * VV];
        }
        __syncthreads();

        float* hp = h_out + (size_t)b * TT * VV;
        const float* hist_f = (const float*)hist;

        for (int t = 0; t < TT; ++t) {
            // pin weights in VGPRs across the back-edge
            asm volatile("" : "+v"(w0), "+v"(w1), "+v"(w2));
            // ---- matvec: uniform-address LDS broadcast of the 16-wide h chunk ----
            float4 hv0 = *(const float4*)&h_lds[k0];
            float4 hv1 = *(const float4*)&h_lds[k0 + 4];
            float4 hv2 = *(const float4*)&h_lds[k0 + 8];
            float4 hv3 = *(const float4*)&h_lds[k0 + 12];
            float a0 = 0.f, a1 = 0.f, a2 = 0.f;
            #define FSTEP(i, hval) \
                a0 = fmaf(hval, w0[i], a0); a1 = fmaf(hval, w1[i], a1); a2 = fmaf(hval, w2[i], a2);
            FSTEP(0, hv0.x)  FSTEP(1, hv0.y)  FSTEP(2, hv0.z)  FSTEP(3, hv0.w)
            FSTEP(4, hv1.x)  FSTEP(5, hv1.y)  FSTEP(6, hv1.z)  FSTEP(7, hv1.w)
            FSTEP(8, hv2.x)  FSTEP(9, hv2.y)  FSTEP(10, hv2.z) FSTEP(11, hv2.w)
            FSTEP(12, hv3.x) FSTEP(13, hv3.y) FSTEP(14, hv3.z) FSTEP(15, hv3.w)
            #undef FSTEP
            if (kg == 2) {
                float g = gam_row[t], rr = r_row[t];
                a0 += fmaf(g, apd0, fmaf(rr, apr0, ab0));
                if (jg == 0) {
                    a1 += fmaf(g, apd1, fmaf(rr, apr1, ab1));
                    a2 += fmaf(g, apd2, fmaf(rr, apr2, ab2));
                } else {
                    a1 += ab1;
                    a2 += ab2;
                }
            }
            P[kg][j0] = a0;
            P[kg][j0 + 64] = a1;
            P[kg][j0 + 128] = a2;
            __syncthreads();

            // ---- gates on threads <128; history flush on the rest ----
            if (tid < VV) {
                int n = tid;
                float ghr = ((P[0][n] + P[1][n]) + (P[2][n] + P[3][n]))
                          + ((P[4][n] + P[5][n]) + (P[6][n] + P[7][n]));
                int nz = n + 128;
                float ghz = ((P[0][nz] + P[1][nz]) + (P[2][nz] + P[3][nz]))
                          + ((P[4][nz] + P[5][nz]) + (P[6][nz] + P[7][nz]));
                int nn2 = n + 256;
                float ghn = ((P[0][nn2] + P[1][nn2]) + (P[2][nn2] + P[3][nn2]))
                          + ((P[4][nn2] + P[5][nn2]) + (P[6][nn2] + P[7][nn2]));
                float g = gam_row[t], rr = r_row[t];
                float r = sigm(ghr);
                float z = sigm(ghz);
                float gin = fmaf(g, pdn, fmaf(rr, prn, bin_));
                float nn = tanh_f(fmaf(r, ghn, gin));
                float h = h_lds[n];
                float hn = fmaf(1.f - z, nn, z * h);
                h_lds[n] = hn;
                hist[t & 15][n] = hn;
            } else if ((t & 7) == 0 && t > 0) {
                int t0 = t - 8;                     // flush slots (t-8..t-1)&15
                int s0 = t0 & 15;                   // contiguous 8-slot group
                for (int i = tid - 128; i < 8 * VV; i += 896)
                    hp[t0 * VV + i] = hist_f[s0 * VV + i];
            }
            __syncthreads();
        }
        // final 8 steps (t = 192..199 -> slots 0..7)
        for (int i = tid; i < 8 * VV; i += 1024)
            hp[192 * VV + i] = hist_f[i];
    } else {
        // ================= memory-scan path (single wave) =================
        int b = blockIdx.x - BB;
        const float* uc = ws + 768;
        const float* ud = ws + 896;
        const float* ur = ws + 1024;
        for (int i = tid; i < KN; i += 1024) C[i] = 0.f;
        if (tid < TT) {
            gam_row[tid] = D_emb[d_seq[b * TT + tid]];
            r_row[tid] = r_seq[b * TT + tid];
            c_row[tid] = c_seq[b * TT + tid];
        }
        __syncthreads();
        if (tid >= 64) return;
        int l = tid;
        float uc0 = uc[l], uc1 = uc[l + 64];
        float ud0 = ud[l], ud1 = ud[l + 64];
        float ur0 = ur[l], ur1 = ur[l + 64];
        float ba0 = b2a[l], ba1 = b2a[l + 64];
        float wb0 = W2b[l], wb1 = W2b[l + 64];
        float bb = b2b[0];
        float* cop = C_out + (size_t)b * TT * KN;
        for (int t = 0; t < TT; ++t) {
            int ct = c_row[t];
            float beta = C[ct];
            float g = gam_row[t], rr = r_row[t];
            float h0 = fmaxf(fmaf(beta, uc0, fmaf(g, ud0, fmaf(rr, ur0, ba0))), 0.f);
            float h1 = fmaxf(fmaf(beta, uc1, fmaf(g, ud1, fmaf(rr, ur1, ba1))), 0.f);
            float p = fmaf(h0, wb0, h1 * wb1);
            #pragma unroll
            for (int m = 32; m > 0; m >>= 1) p += __shfl_xor(p, m);
            float nc = p + bb;
            if (l == 0) C[ct] = nc;
            float* rowp = cop + (size_t)t * KN;
            #pragma unroll
            for (int s = 0; s < 8; ++s) {
                int idx = 256 * s + 4 * l;
                if (s < 7 || l < 52) {
                    float4 v = *(const float4*)&C[idx];
                    *(float4*)&rowp[idx] = v;
                }
            }
        }
    }
}

// ---------------- alpha head: bf16 MFMA, fragments loaded straight from global -
__device__ __forceinline__ short f2bf(float f) {
    uint32_t u = __float_as_uint(f);
    u = (u + 0x7FFFu + ((u >> 16) & 1u)) >> 16;
    return (short)u;
}
__device__ __forceinline__ bf16x8 load_cvt8(const float* p) {
    float4 a = *(const float4*)p;
    float4 c = *(const float4*)(p + 4);
    bf16x8 r;
    r[0] = f2bf(a.x); r[1] = f2bf(a.y); r[2] = f2bf(a.z); r[3] = f2bf(a.w);
    r[4] = f2bf(c.x); r[5] = f2bf(c.y); r[6] = f2bf(c.z); r[7] = f2bf(c.w);
    return r;
}

__global__ void alpha_kernel(const float* __restrict__ h_seq, const float* __restrict__ W1a,
                             const float* __restrict__ b1a, const float* __restrict__ W1b,
                             const float* __restrict__ b1b, float* __restrict__ alpha)
{
    int wave = threadIdx.x >> 6;
    int lane = threadIdx.x & 63;
    int tile = blockIdx.x * 4 + wave;  // 800 tiles of 16 rows
    int rowbase = tile * 16;
    int rl = lane & 15, g = lane >> 4;
    const float* hp = h_seq + (size_t)(rowbase + rl) * VV + g * 8;
    bf16x8 a0 = load_cvt8(hp);
    bf16x8 a1 = load_cvt8(hp + 32);
    bf16x8 a2 = load_cvt8(hp + 64);
    bf16x8 a3 = load_cvt8(hp + 96);
    float p0 = 0.f, p1 = 0.f, p2 = 0.f, p3 = 0.f;
    float bb = b1b[0];
    #pragma unroll
    for (int jt = 0; jt < 8; ++jt) {
        int j = jt * 16 + rl;
        const float* wp = W1a + (size_t)j * VV + g * 8;
        f32x4 acc = {0.f, 0.f, 0.f, 0.f};
        acc = __builtin_amdgcn_mfma_f32_16x16x32_bf16(a0, load_cvt8(wp), acc, 0, 0, 0);
        acc = __builtin_amdgcn_mfma_f32_16x16x32_bf16(a1, load_cvt8(wp + 32), acc, 0, 0, 0);
        acc = __builtin_amdgcn_mfma_f32_16x16x32_bf16(a2, load_cvt8(wp + 64), acc, 0, 0, 0);
        acc = __builtin_amdgcn_mfma_f32_16x16x32_bf16(a3, load_cvt8(wp + 96), acc, 0, 0, 0);
        float bj = b1a[j], wj = W1b[j];
        p0 += fmaxf(acc[0] + bj, 0.f) * wj;
        p1 += fmaxf(acc[1] + bj, 0.f) * wj;
        p2 += fmaxf(acc[2] + bj, 0.f) * wj;
        p3 += fmaxf(acc[3] + bj, 0.f) * wj;
    }
    #pragma unroll
    for (int m = 1; m < 16; m <<= 1) {
        p0 += __shfl_xor(p0, m);
        p1 += __shfl_xor(p1, m);
        p2 += __shfl_xor(p2, m);
        p3 += __shfl_xor(p3, m);
    }
    if (rl == 0) {
        alpha[rowbase + g * 4 + 0] = p0 + bb;
        alpha[rowbase + g * 4 + 1] = p1 + bb;
        alpha[rowbase + g * 4 + 2] = p2 + bb;
        alpha[rowbase + g * 4 + 3] = p3 + bb;
    }
}

extern "C" void kernel_launch(void* const* d_in, const int* in_sizes, int n_in,
                              void* d_out, int out_size, void* d_ws, size_t ws_size,
                              hipStream_t stream)
{
    const int*   c_seq = (const int*)d_in[0];
    const int*   d_seq = (const int*)d_in[1];
    const float* r_seq = (const float*)d_in[2];
    const float* D_emb = (const float*)d_in[3];
    const float* v_d   = (const float*)d_in[4];
    const float* v_r   = (const float*)d_in[5];
    const float* v_c   = (const float*)d_in[6];
    const float* W_ih  = (const float*)d_in[7];
    const float* W_hh  = (const float*)d_in[8];
    const float* b_ih  = (const float*)d_in[9];
    const float* b_hh  = (const float*)d_in[10];
    const float* W1a   = (const float*)d_in[11];
    const float* b1a   = (const float*)d_in[12];
    const float* W1b   = (const float*)d_in[13];
    const float* b1b   = (const float*)d_in[14];
    const float* W2a   = (const float*)d_in[15];
    const float* b2a   = (const float*)d_in[16];
    const float* W2b   = (const float*)d_in[17];
    const float* b2b   = (const float*)d_in[18];

    float* out   = (float*)d_out;
    float* alpha = out;                       // 12800
    float* h_seq = out + 12800;               // 1,638,400
    float* C_out = out + 12800 + 1638400;     // 25,600,000
    float* ws    = (float*)d_ws;

    hipLaunchKernelGGL(pre_kernel, dim3(2), dim3(256), 0, stream,
                       v_d, v_r, v_c, W_ih, W2a, ws);
    hipLaunchKernelGGL(fused_kernel, dim3(BB * 2), dim3(1024), 0, stream,
                       c_seq, d_seq, r_seq, D_emb, W_hh, b_ih, b_hh,
                       W2b, b2a, b2b, ws, C_out, h_seq);
    hipLaunchKernelGGL(alpha_kernel, dim3(200), dim3(256), 0, stream,
                       h_seq, W1a, b1a, W1b, b1b, alpha);
}